// Round 1
// baseline (943.040 us; speedup 1.0000x reference)
//
#include <hip/hip_runtime.h>
#include <hip/hip_bf16.h>

// RecurrentOjaUpdateRule on MI355X.
// Memory floor: read W (512MB) + write out (512MB) ~= 170us @ 6.3TB/s.
// GEMM chain done with 3-pass bf16-split MFMA (fp32-equivalent accuracy).

typedef __bf16 bf16_t;
typedef __bf16 bf16x8 __attribute__((ext_vector_type(8)));
typedef float f32x4 __attribute__((ext_vector_type(4)));

// ---------------- prep: split fp32 -> bf16 hi/lo ----------------
__global__ __launch_bounds__(256) void k_split(const float* __restrict__ src,
                                               bf16_t* __restrict__ hi,
                                               bf16_t* __restrict__ lo, int n) {
  int i = blockIdx.x * 256 + threadIdx.x;
  if (i < n) {
    float v = src[i];
    bf16_t h = (bf16_t)v;
    hi[i] = h;
    lo[i] = (bf16_t)(v - (float)h);
  }
}

// z -> columns 512..1023 of the 4096x1024 concat buffer
__global__ __launch_bounds__(256) void k_split_z(const float* __restrict__ z,
                                                 bf16_t* __restrict__ xz_hi,
                                                 bf16_t* __restrict__ xz_lo) {
  int i = blockIdx.x * 256 + threadIdx.x;  // over 4096*512
  int r = i >> 9, c = i & 511;
  size_t o = ((size_t)r << 10) + 512 + c;
  float v = z[i];
  bf16_t h = (bf16_t)v;
  xz_hi[o] = h;
  xz_lo[o] = (bf16_t)(v - (float)h);
}

// W (KxN fp32 row-major) -> Wt (Npad x K bf16 hi/lo), zero pad rows n>=N.
__global__ __launch_bounds__(256) void k_transpose_split(const float* __restrict__ src,
                                                         bf16_t* __restrict__ dst_hi,
                                                         bf16_t* __restrict__ dst_lo,
                                                         int K, int N) {
  __shared__ float tile[32][33];
  int k0 = blockIdx.x * 32;
  int n0 = blockIdx.y * 32;
  int tx = threadIdx.x, ty = threadIdx.y;  // (32,8)
#pragma unroll
  for (int i = 0; i < 32; i += 8) {
    int k = k0 + ty + i, n = n0 + tx;
    tile[ty + i][tx] = (n < N) ? src[(size_t)k * N + n] : 0.0f;
  }
  __syncthreads();
#pragma unroll
  for (int i = 0; i < 32; i += 8) {
    int n = n0 + ty + i, k = k0 + tx;
    float v = tile[tx][ty + i];
    bf16_t h = (bf16_t)v;
    dst_hi[(size_t)n * K + k] = h;
    dst_lo[(size_t)n * K + k] = (bf16_t)(v - (float)h);
  }
}

// ---------------- 3-pass bf16-split MFMA GEMM ----------------
// C[M][Nc] = A[M][K] * Bt[N][K]^T (+bias). Tile 64x64, BK=64, 256 threads.
// EPI: 0 = store fp32, 1 = +bias store fp32, 2 = +bias split to bf16 hi/lo.
template <int EPI>
__global__ __launch_bounds__(256) void k_gemm(
    const bf16_t* __restrict__ Ahi, const bf16_t* __restrict__ Alo,
    const bf16_t* __restrict__ Bhi, const bf16_t* __restrict__ Blo,
    const float* __restrict__ bias, float* __restrict__ Cf,
    bf16_t* __restrict__ Chi, bf16_t* __restrict__ Clo, int K, int Nc) {
  constexpr int LDK = 72;  // 64 + 8 bf16 pad: keeps 16B alignment, ~2-way banks (free)
  __shared__ bf16_t sAh[64 * LDK], sAl[64 * LDK], sBh[64 * LDK], sBl[64 * LDK];
  const int m0 = blockIdx.x * 64, n0 = blockIdx.y * 64;
  const int t = threadIdx.x;
  const int lane = t & 63, wave = t >> 6;
  const int wm = (wave & 1) * 32, wn = (wave >> 1) * 32;
  const int lm = lane & 15, q = lane >> 4;

  f32x4 acc[2][2] = {{{0.f, 0.f, 0.f, 0.f}, {0.f, 0.f, 0.f, 0.f}},
                     {{0.f, 0.f, 0.f, 0.f}, {0.f, 0.f, 0.f, 0.f}}};

  // staging: each of 4 LDS arrays is 512 16B-chunks; thread does chunks t, t+256
  const int r0 = t >> 3, r1 = (t + 256) >> 3, cc = t & 7;
  const size_t gA0 = (size_t)(m0 + r0) * K + cc * 8;
  const size_t gA1 = (size_t)(m0 + r1) * K + cc * 8;
  const size_t gB0 = (size_t)(n0 + r0) * K + cc * 8;
  const size_t gB1 = (size_t)(n0 + r1) * K + cc * 8;
  const int s0 = r0 * LDK + cc * 8;
  const int s1 = r1 * LDK + cc * 8;

  for (int k0 = 0; k0 < K; k0 += 64) {
    __syncthreads();
    *(uint4*)&sAh[s0] = *(const uint4*)&Ahi[gA0 + k0];
    *(uint4*)&sAh[s1] = *(const uint4*)&Ahi[gA1 + k0];
    *(uint4*)&sAl[s0] = *(const uint4*)&Alo[gA0 + k0];
    *(uint4*)&sAl[s1] = *(const uint4*)&Alo[gA1 + k0];
    *(uint4*)&sBh[s0] = *(const uint4*)&Bhi[gB0 + k0];
    *(uint4*)&sBh[s1] = *(const uint4*)&Bhi[gB1 + k0];
    *(uint4*)&sBl[s0] = *(const uint4*)&Blo[gB0 + k0];
    *(uint4*)&sBl[s1] = *(const uint4*)&Blo[gB1 + k0];
    __syncthreads();
#pragma unroll
    for (int ks = 0; ks < 64; ks += 32) {
      bf16x8 ah[2], al[2], bh[2], bl[2];
#pragma unroll
      for (int i = 0; i < 2; ++i) {
        int ra = (wm + i * 16 + lm) * LDK + ks + q * 8;
        int rb = (wn + i * 16 + lm) * LDK + ks + q * 8;
        ah[i] = *(const bf16x8*)&sAh[ra];
        al[i] = *(const bf16x8*)&sAl[ra];
        bh[i] = *(const bf16x8*)&sBh[rb];
        bl[i] = *(const bf16x8*)&sBl[rb];
      }
#pragma unroll
      for (int i = 0; i < 2; ++i)
#pragma unroll
        for (int j = 0; j < 2; ++j) {
          acc[i][j] = __builtin_amdgcn_mfma_f32_16x16x32_bf16(ah[i], bh[j], acc[i][j], 0, 0, 0);
          acc[i][j] = __builtin_amdgcn_mfma_f32_16x16x32_bf16(ah[i], bl[j], acc[i][j], 0, 0, 0);
          acc[i][j] = __builtin_amdgcn_mfma_f32_16x16x32_bf16(al[i], bh[j], acc[i][j], 0, 0, 0);
        }
    }
  }
  // epilogue: D[row=q*4+r][col=lane&15] (verified m89/m91 C/D layout)
#pragma unroll
  for (int i = 0; i < 2; ++i)
#pragma unroll
    for (int j = 0; j < 2; ++j) {
      int col = n0 + wn + j * 16 + lm;
      if (col < Nc) {
        float bv = (EPI >= 1) ? bias[col] : 0.0f;
#pragma unroll
        for (int r = 0; r < 4; ++r) {
          int row = m0 + wm + i * 16 + q * 4 + r;
          float v = acc[i][j][r] + bv;
          size_t o = (size_t)row * Nc + col;
          if (EPI == 2) {
            bf16_t h = (bf16_t)v;
            Chi[o] = h;
            Clo[o] = (bf16_t)(v - (float)h);
          } else {
            Cf[o] = v;
          }
        }
      }
    }
}

// ---------------- LayerNorm (+ip_b) -> bf16 hi/lo into concat cols 0..511 ----
__global__ __launch_bounds__(256) void k_ln_split(const float* __restrict__ hraw,
                                                  const float* __restrict__ ipb,
                                                  const float* __restrict__ g,
                                                  const float* __restrict__ be,
                                                  bf16_t* __restrict__ xz_hi,
                                                  bf16_t* __restrict__ xz_lo) {
  int row = blockIdx.x, t = threadIdx.x;
  float2 v2 = ((const float2*)(hraw + ((size_t)row << 9)))[t];
  float a = v2.x + ipb[2 * t];
  float b = v2.y + ipb[2 * t + 1];
  float s = a + b, ss = a * a + b * b;
#pragma unroll
  for (int off = 32; off > 0; off >>= 1) {
    s += __shfl_xor(s, off);
    ss += __shfl_xor(ss, off);
  }
  __shared__ float red[8];
  int w = t >> 6;
  if ((t & 63) == 0) { red[w] = s; red[4 + w] = ss; }
  __syncthreads();
  s = red[0] + red[1] + red[2] + red[3];
  ss = red[4] + red[5] + red[6] + red[7];
  float mu = s * (1.0f / 512.0f);
  float var = ss * (1.0f / 512.0f) - mu * mu;
  float rs = rsqrtf(var + 1e-5f);
  float o0 = (a - mu) * rs * g[2 * t] + be[2 * t];
  float o1 = (b - mu) * rs * g[2 * t + 1] + be[2 * t + 1];
  size_t o = ((size_t)row << 10) + 2 * t;
  bf16_t h0 = (bf16_t)o0;
  xz_hi[o] = h0;
  xz_lo[o] = (bf16_t)(o0 - (float)h0);
  bf16_t h1 = (bf16_t)o1;
  xz_hi[o + 1] = h1;
  xz_lo[o + 1] = (bf16_t)(o1 - (float)h1);
}

// ---------------- final: per (b,h) 64x64 tile: Oja update ----------------
// ks_remove = vs^T W; ks = softmax(k - ks_remove)*sigmoid(lr); out = vs ks^T + W
__global__ __launch_bounds__(256) void k_final(const float* __restrict__ kvb,
                                               const float* __restrict__ W,
                                               float* __restrict__ out) {
  int bh = blockIdx.x;
  int b = bh >> 3, h = bh & 7;
  const float* kb = kvb + (size_t)b * 1032 + h * 129;
  const float* Wt = W + (size_t)bh * 4096;
  float* Ot = out + (size_t)bh * 4096;
  __shared__ float vsS[64], kS[64], prS[1024], ksfS[64];
  __shared__ float lrS;
  int t = threadIdx.x;
  if (t < 64) kS[t] = kb[t];
  else if (t < 128) vsS[t - 64] = tanhf(kb[t]);  // kb[64 + (t-64)]
  else if (t == 128) lrS = 1.0f / (1.0f + expf(-kb[128]));

  // W tile: thread t holds float4 chunks t, t+256, t+512, t+768
  // chunk f: row d = f/16, cols 4*(f%16).. -> rows d0+16k, colgrp c
  const float4* W4 = (const float4*)Wt;
  float4 w0 = W4[t], w1 = W4[t + 256], w2 = W4[t + 512], w3 = W4[t + 768];
  __syncthreads();

  int c = t & 15, d0 = t >> 4;
  float v0 = vsS[d0], v1 = vsS[d0 + 16], v2 = vsS[d0 + 32], v3 = vsS[d0 + 48];
  float4 p;
  p.x = w0.x * v0 + w1.x * v1 + w2.x * v2 + w3.x * v3;
  p.y = w0.y * v0 + w1.y * v1 + w2.y * v2 + w3.y * v3;
  p.z = w0.z * v0 + w1.z * v1 + w2.z * v2 + w3.z * v3;
  p.w = w0.w * v0 + w1.w * v1 + w2.w * v2 + w3.w * v3;
  ((float4*)prS)[t] = p;
  __syncthreads();

  if (t < 64) {  // wave 0: reduce partials, softmax over 64 lanes
    int cg = t >> 2, qq = t & 3;
    float rem = 0.0f;
#pragma unroll
    for (int r = 0; r < 16; ++r) rem += prS[(r * 16 + cg) * 4 + qq];
    float logit = kS[t] - rem;
    float m = logit;
#pragma unroll
    for (int off = 32; off > 0; off >>= 1) m = fmaxf(m, __shfl_xor(m, off));
    float ex = expf(logit - m);
    float sum = ex;
#pragma unroll
    for (int off = 32; off > 0; off >>= 1) sum += __shfl_xor(sum, off);
    ksfS[t] = ex / sum * lrS;
  }
  __syncthreads();

  float4 kf = *(const float4*)&ksfS[c * 4];
  float4* O4 = (float4*)Ot;
  float4 o;
  o.x = v0 * kf.x + w0.x; o.y = v0 * kf.y + w0.y; o.z = v0 * kf.z + w0.z; o.w = v0 * kf.w + w0.w;
  O4[t] = o;
  o.x = v1 * kf.x + w1.x; o.y = v1 * kf.y + w1.y; o.z = v1 * kf.z + w1.z; o.w = v1 * kf.w + w1.w;
  O4[t + 256] = o;
  o.x = v2 * kf.x + w2.x; o.y = v2 * kf.y + w2.y; o.z = v2 * kf.z + w2.z; o.w = v2 * kf.w + w2.w;
  O4[t + 512] = o;
  o.x = v3 * kf.x + w3.x; o.y = v3 * kf.y + w3.y; o.z = v3 * kf.z + w3.z; o.w = v3 * kf.w + w3.w;
  O4[t + 768] = o;
}

extern "C" void kernel_launch(void* const* d_in, const int* in_sizes, int n_in,
                              void* d_out, int out_size, void* d_ws, size_t ws_size,
                              hipStream_t stream) {
  (void)in_sizes; (void)n_in; (void)out_size; (void)ws_size;
  const float* x     = (const float*)d_in[0];
  const float* z     = (const float*)d_in[1];
  const float* W     = (const float*)d_in[2];
  const float* ip_w  = (const float*)d_in[3];
  const float* ip_b  = (const float*)d_in[4];
  const float* ln_g  = (const float*)d_in[5];
  const float* ln_b  = (const float*)d_in[6];
  const float* mg_w  = (const float*)d_in[7];
  const float* mg_b  = (const float*)d_in[8];
  const float* kvb_w = (const float*)d_in[9];
  const float* kvb_b = (const float*)d_in[10];
  float* out = (float*)d_out;
  char* ws = (char*)d_ws;

  // workspace layout (bytes); kvb overlays x/xz which are dead by GEMM3
  bf16_t* x_hi     = (bf16_t*)(ws + 0);         // 4 MB
  bf16_t* x_lo     = (bf16_t*)(ws + 4194304);   // 4 MB
  bf16_t* xz_hi    = (bf16_t*)(ws + 8388608);   // 8 MB (4096x1024)
  bf16_t* xz_lo    = (bf16_t*)(ws + 16777216);  // 8 MB
  bf16_t* ipwt_hi  = (bf16_t*)(ws + 25165824);  // 512 KB (512x512 NxK)
  bf16_t* ipwt_lo  = (bf16_t*)(ws + 25690112);
  bf16_t* mgwt_hi  = (bf16_t*)(ws + 26214400);  // 1 MB (512x1024 NxK)
  bf16_t* mgwt_lo  = (bf16_t*)(ws + 27262976);
  bf16_t* kvbwt_hi = (bf16_t*)(ws + 28311552);  // 1.125 MB (1152x512 NxK, padded)
  bf16_t* kvbwt_lo = (bf16_t*)(ws + 29491200);
  float*  hraw     = (float*)(ws + 30670848);   // 8 MB (4096x512)
  bf16_t* h2_hi    = (bf16_t*)(ws + 39059456);  // 4 MB
  bf16_t* h2_lo    = (bf16_t*)(ws + 43253760);  // 4 MB  (end 47,448,064)
  float*  kvb      = (float*)(ws + 0);          // 16.9 MB, overlays dead x/xz

  // prep
  k_split<<<8192, 256, 0, stream>>>(x, x_hi, x_lo, 4096 * 512);
  k_split_z<<<8192, 256, 0, stream>>>(z, xz_hi, xz_lo);
  k_transpose_split<<<dim3(16, 16), dim3(32, 8), 0, stream>>>(ip_w, ipwt_hi, ipwt_lo, 512, 512);
  k_transpose_split<<<dim3(32, 16), dim3(32, 8), 0, stream>>>(mg_w, mgwt_hi, mgwt_lo, 1024, 512);
  k_transpose_split<<<dim3(16, 36), dim3(32, 8), 0, stream>>>(kvb_w, kvbwt_hi, kvbwt_lo, 512, 1032);

  // GEMM1: h_raw = x @ ip_w    (M=4096,N=512,K=512)
  k_gemm<0><<<dim3(64, 8), 256, 0, stream>>>(x_hi, x_lo, ipwt_hi, ipwt_lo,
                                             nullptr, hraw, nullptr, nullptr, 512, 512);
  // LN(+ip_b) -> concat cols 0..511
  k_ln_split<<<4096, 256, 0, stream>>>(hraw, ip_b, ln_g, ln_b, xz_hi, xz_lo);
  // GEMM2: h2 = [h,z] @ mg_w + mg_b   (K=1024)
  k_gemm<2><<<dim3(64, 8), 256, 0, stream>>>(xz_hi, xz_lo, mgwt_hi, mgwt_lo,
                                             mg_b, nullptr, h2_hi, h2_lo, 1024, 512);
  // GEMM3: kvb = h2 @ kvb_w + kvb_b   (N=1032, padded to 17*64=1088 tiles)
  k_gemm<1><<<dim3(64, 17), 256, 0, stream>>>(h2_hi, h2_lo, kvbwt_hi, kvbwt_lo,
                                              kvb_b, kvb, nullptr, nullptr, 512, 1032);
  // final Oja update
  k_final<<<32768, 256, 0, stream>>>(kvb, W, out);
}